// Round 10
// baseline (234.241 us; speedup 1.0000x reference)
//
#include <hip/hip_runtime.h>
#include <math.h>

// RiemannianLayerNormV2: x (8,4096,1025) f32 -> out (8,4096,1025) f32
// R10 = R7 resubmitted (repeated GPU acquisition timeouts; never ran).
// Vectorized HBM access via block-cooperative float4 staging:
//   - 4 rows/block = 4100 floats = 1025 float4, 16B-aligned for EVERY block
//   - stage HBM->LDS as float4 (sanitized), per-wave row work from LDS,
//     results back into same LDS buffer, cooperative float4 store.
//   - rows are wave-private in LDS after staging -> only 2 barriers.
//   - DPP wave reductions; var from first-pass moments (1 tree deleted).

#define NROWS (8 * 4096)
#define DD 1024
#define KPL 16               // 1024 / 64
#define RPB 4                // rows per block
#define BLOCK (RPB * 64)
#define ROWLEN 1025
#define CHUNK (RPB * ROWLEN) // 4100 floats = 16400 B = 1025 float4

__device__ __forceinline__ float sanitize_in(float x) {
    // nan->0, +inf->1e4, -inf->-1e4, finite passthrough
    if (!__builtin_isfinite(x)) x = __builtin_isnan(x) ? 0.0f : (x > 0.0f ? 1.0e4f : -1.0e4f);
    return x;
}

__device__ __forceinline__ float4 sanitize4(float4 v) {
    v.x = sanitize_in(v.x);
    v.y = sanitize_in(v.y);
    v.z = sanitize_in(v.z);
    v.w = sanitize_in(v.w);
    return v;
}

template <int CTRL, int ROW_MASK>
__device__ __forceinline__ float dpp_add(float x) {
    int y = __builtin_amdgcn_update_dpp(0, __builtin_bit_cast(int, x),
                                        CTRL, ROW_MASK, 0xf, false);
    return x + __builtin_bit_cast(float, y);
}

// 64-lane sum, result broadcast via readlane(63)
__device__ __forceinline__ float wave_sum(float x) {
    x = dpp_add<0x111, 0xf>(x);  // row_shr:1
    x = dpp_add<0x112, 0xf>(x);  // row_shr:2
    x = dpp_add<0x114, 0xf>(x);  // row_shr:4
    x = dpp_add<0x118, 0xf>(x);  // row_shr:8
    x = dpp_add<0x142, 0xa>(x);  // row_bcast:15
    x = dpp_add<0x143, 0xc>(x);  // row_bcast:31 -> lane63 = total
    return __builtin_bit_cast(float, __builtin_amdgcn_readlane(__builtin_bit_cast(int, x), 63));
}

__global__ void __launch_bounds__(BLOCK)
rln_kernel(const float* __restrict__ x, const float* __restrict__ gamma,
           const float* __restrict__ beta, float* __restrict__ out) {
    __shared__ float s_buf[CHUNK];   // 16400 B: in-place row buffer
    __shared__ float s_g[DD];        // 4 KB
    __shared__ float s_b[DD];        // 4 KB

    const int tid = threadIdx.x;

    // ---- cooperative vectorized stage: HBM -> LDS (sanitized) ----
    const float4* gsrc = reinterpret_cast<const float4*>(x) + (size_t)blockIdx.x * 1025;
    float4* sbuf4 = reinterpret_cast<float4*>(s_buf);
#pragma unroll
    for (int i = 0; i < 4; ++i)
        sbuf4[tid + i * 256] = sanitize4(gsrc[tid + i * 256]);
    if (tid == 0) sbuf4[1024] = sanitize4(gsrc[1024]);
    reinterpret_cast<float4*>(s_g)[tid] = reinterpret_cast<const float4*>(gamma)[tid];
    reinterpret_cast<float4*>(s_b)[tid] = reinterpret_cast<const float4*>(beta)[tid];
    __syncthreads();

    // ---- per-wave row (wave-private LDS region from here on) ----
    const int wave = tid >> 6;
    const int lane = tid & 63;
    float* srow = s_buf + wave * ROWLEN;

    // pass 1: x0 + xs, fused (sum, sumsq)
    float x0 = srow[0];                     // same-addr broadcast
    float xv[KPL];
    float p_sum = 0.0f, p_sq = 0.0f;
#pragma unroll
    for (int k = 0; k < KPL; ++k) {
        float t = srow[1 + lane + k * 64];  // consecutive banks: conflict-free
        xv[k] = t;
        p_sum += t;
        p_sq  = fmaf(t, t, p_sq);
    }
    const float sum   = wave_sum(p_sum);
    const float sumsq = wave_sum(p_sq);

    const float dist = acoshf(fmaxf(x0, 1.0000001192092896f));  // clip(x0, 1+1e-7)
    const float rn   = fmaxf(sqrtf(sumsq), 1e-7f);
    const float s    = dist / rn;
    const float mu   = s * sum * (1.0f / DD);
    // var = s^2 * sumsq/D - mu^2  (mu^2 << var on this data)
    const float var  = fmaf(s * s, sumsq * (1.0f / DD), -mu * mu);
    const float rstd = rsqrtf(var + 1e-5f);

    // pass 2: v_norm + clip, accumulate n^2
    float nsq = 0.0f;
#pragma unroll
    for (int k = 0; k < KPL; ++k) {
        const int j = lane + k * 64;
        float t  = fmaf(s, xv[k], -mu) * rstd;
        float vn = fmaf(t, s_g[j], s_b[j]);
        vn = fminf(fmaxf(vn, -5.0f), 5.0f);
        xv[k] = vn;
        nsq = fmaf(vn, vn, nsq);
    }
    nsq = wave_sum(nsq);

    const float n  = sqrtf(nsq);
    const float nc = fminf(fmaxf(n, 1e-7f), 1.5f);
    const float ss = sinhf(nc) / fmaxf(n, 1e-7f);

    // write results back into the (wave-private) LDS row
#pragma unroll
    for (int k = 0; k < KPL; ++k)
        srow[1 + lane + k * 64] = ss * xv[k];
    if (lane == 0)
        srow[0] = sqrtf(fmaf(ss * ss, nsq, 1.0f));
    __syncthreads();

    // ---- cooperative vectorized store: LDS -> HBM ----
    float4* gdst = reinterpret_cast<float4*>(out) + (size_t)blockIdx.x * 1025;
#pragma unroll
    for (int i = 0; i < 4; ++i)
        gdst[tid + i * 256] = sbuf4[tid + i * 256];
    if (tid == 0) gdst[1024] = sbuf4[1024];
}

extern "C" void kernel_launch(void* const* d_in, const int* in_sizes, int n_in,
                              void* d_out, int out_size, void* d_ws, size_t ws_size,
                              hipStream_t stream) {
    const float* x     = (const float*)d_in[0];
    const float* gamma = (const float*)d_in[1];
    const float* beta  = (const float*)d_in[2];
    float* out = (float*)d_out;
    rln_kernel<<<NROWS / RPB, BLOCK, 0, stream>>>(x, gamma, beta, out);
}